// Round 4
// baseline (57.081 us; speedup 1.0000x reference)
//
#include <hip/hip_runtime.h>

// out[o,h,w] = sum_i  (w>0) * x[i, (h-1)%14, (w-2)%14] * wt[o,0,i]
//            +        x[i, (h-1)%14, (w-1)%14] * wt[o,1,i]
//            + (w<13)* x[i, (h-1)%14,  w     ] * wt[o,2,i]
//
// x  : [128, 14, 14] f32, wt : [32, 3, 128] f32, out: [32, 14, 14] f32
//
// Round 4: single-wave blocks. 448 blocks (one per (o,h) row) x 64 threads.
// 56 active lanes = 14 columns x 4 channel-groups of 32 channels. Reduction
// across the 4 groups via shfl_xor inside the wave -> no LDS, no barrier,
// one dispatch round (448 waves co-resident on 256 CUs).

__global__ __launch_bounds__(64) void conv_roll_kernel(
    const float* __restrict__ x,
    const float* __restrict__ wt,
    float* __restrict__ out)
{
    const int bx = blockIdx.x;        // 0..447
    const int o  = bx / 14;           // 0..31 (uniform)
    const int h  = bx - o * 14;       // 0..13 (uniform)
    const int hh = (h + 13) % 14;     // undo output H-roll
    const int rb = hh * 14;

    const int lane = threadIdx.x;     // 0..63
    if (lane >= 56) return;           // groups of 4 all within lanes 0..55
    const int w = lane >> 2;          // output column 0..13
    const int g = lane & 3;           // channel group 0..3 (32 ch each)

    const int c0 = rb + ((w + 12) % 14);   // k=0 tap column
    const int c1 = rb + ((w + 13) % 14);   // k=1 tap (always valid)
    const int c2 = rb + w;                 // k=2 tap column

    const float* __restrict__ wo = wt + o * 384 + g * 32;  // [3][32] slice
    const float* __restrict__ xb = x + (g * 32) * 196;

    float a0 = 0.f, a1 = 0.f, a2 = 0.f;
#pragma unroll
    for (int j = 0; j < 32; ++j) {
        const float* __restrict__ xp = xb + j * 196;
        a0 = __builtin_fmaf(xp[c0], wo[j],       a0);
        a1 = __builtin_fmaf(xp[c1], wo[128 + j], a1);
        a2 = __builtin_fmaf(xp[c2], wo[256 + j], a2);
    }

    const float m0 = (w > 0)  ? 1.0f : 0.0f;   // left zero-pad mask
    const float m2 = (w < 13) ? 1.0f : 0.0f;   // right zero-pad mask
    float s = m0 * a0 + a1 + m2 * a2;

    // butterfly reduce over the 4-lane channel-group
    s += __shfl_xor(s, 1);
    s += __shfl_xor(s, 2);

    if (g == 0) out[o * 196 + h * 14 + w] = s;
}

extern "C" void kernel_launch(void* const* d_in, const int* in_sizes, int n_in,
                              void* d_out, int out_size, void* d_ws, size_t ws_size,
                              hipStream_t stream) {
    const float* x  = (const float*)d_in[0];   // 128*14*14 = 25088
    const float* wt = (const float*)d_in[1];   // 32*3*128  = 12288
    float* out = (float*)d_out;                // 32*14*14  = 6272

    conv_roll_kernel<<<448, 64, 0, stream>>>(x, wt, out);
}